// Round 1
// baseline (841.832 us; speedup 1.0000x reference)
//
#include <hip/hip_runtime.h>
#include <math.h>

// PQC simulator: 16 qubits, 4 layers, batch 256.
// State stored as float2 (re,im) in d_out, indexed by "storage index" s which is
// the FINAL logical index (all CNOT-chain permutations deferred & pre-composed).
//   storage[s] initially = in[gray4(s)],  gray4(s)=s^(s>>4)
//   gate (layer t, qubit q) acts on pairs {s, s^m'},  m' = prefixXOR^(4-t)(e_q)
//   role(s) (is s the logical-|1> side?) = parity(w' & s), w' = row of gray^(4-t)
// Gates are applied in 13 passes of 5 (last 4) gates; each thread owns a
// 32-amplitude XOR-coset in registers. All tables are constexpr.

#define NLAYERS 4
#define NBATCH 256

struct PassT {
    int ng;
    int gidx[5];
    unsigned m[5];      // pair masks (storage space)
    unsigned w[5];      // role functionals
    unsigned lam[5];    // lam[g] bit k = parity(w[g] & m[k])  (cross-layer role terms)
    unsigned freemask;  // complement (non-pivot) bit positions for coset enumeration
    unsigned combo[32]; // XOR combos of masks
};

constexpr unsigned mprime(int t, int q) {
    // prefixXOR^(u)(e_q), u = 4-t ; bit position b = 15-q ; bits b-s where C(u-1+s,s) odd
    int u = NLAYERS - t, b = 15 - q;
    unsigned m = 0;
    for (int s = 0; s <= b; ++s) {
        int n = u - 1 + s;
        if ((n & s) == s) m |= 1u << (b - s);   // Lucas: C(n,s) odd iff (n&s)==s
    }
    return m;
}
constexpr unsigned wprime(int t, int q) {
    // row of gray^(u), u = 4-t : bits b+i where C(u,i) odd
    int u = NLAYERS - t, b = 15 - q;
    unsigned w = 0;
    for (int i = 0; b + i <= 15; ++i)
        if ((u & i) == i) w |= 1u << (b + i);
    return w;
}
constexpr int parity16(unsigned x) {
    int p = 0;
    for (int j = 0; j < 16; ++j) p ^= (int)((x >> j) & 1u);
    return p;
}

constexpr PassT make_pass(int p) {
    PassT pt{};
    int start = p * 5;
    pt.ng = (p < 12) ? 5 : 4;
    for (int g = 0; g < pt.ng; ++g) {
        int gi = start + g;
        int t = gi / 16, q = gi % 16;
        pt.gidx[g] = gi;
        pt.m[g] = mprime(t, q);
        pt.w[g] = wprime(t, q);
    }
    for (int g = 0; g < pt.ng; ++g) {
        unsigned l = 0;
        for (int k = 0; k < pt.ng; ++k)
            l |= (unsigned)parity16(pt.w[g] & pt.m[k]) << k;
        pt.lam[g] = l;
    }
    // Gaussian elimination -> pivot bits; freemask = non-pivot positions
    unsigned red[5] = {0, 0, 0, 0, 0};
    int pb[5] = {0, 0, 0, 0, 0};
    unsigned piv = 0;
    for (int g = 0; g < pt.ng; ++g) {
        unsigned r = pt.m[g];
        for (int h = 0; h < g; ++h)
            if ((r >> pb[h]) & 1u) r ^= red[h];
        int b = 15;
        while (b > 0 && !((r >> b) & 1u)) --b;
        red[g] = r; pb[g] = b; piv |= 1u << b;
    }
    pt.freemask = 0xFFFFu ^ piv;
    for (int v = 0; v < (1 << pt.ng); ++v) {
        unsigned c = 0;
        for (int g = 0; g < pt.ng; ++g)
            if ((v >> g) & 1) c ^= pt.m[g];
        pt.combo[v] = c;
    }
    return pt;
}

// ---- prep: fuse RZ*RY*RX per (layer,qubit) into 8 floats in d_ws ----
__global__ void prep_gates(const float* __restrict__ params, float* __restrict__ utab) {
    int i = threadIdx.x;
    if (i >= 64) return;
    int t = i >> 4, q = i & 15;
    float ax = params[(t * 16 + q) * 3 + 0];
    float ay = params[(t * 16 + q) * 3 + 1];
    float az = params[(t * 16 + q) * 3 + 2];
    float cx = cosf(0.5f * ax), sx = sinf(0.5f * ax);
    float cy = cosf(0.5f * ay), sy = sinf(0.5f * ay);
    float cz = cosf(0.5f * az), sz = sinf(0.5f * az);
    // RY*RX = [[A+iB, -C-iD],[C-iD, A-iB]]
    float A = cy * cx, B = sy * sx, C = sy * cx, D = cy * sx;
    float* o = utab + i * 8;
    // u00 = (cz-isz)(A+iB)
    o[0] = cz * A + sz * B;  o[1] = cz * B - sz * A;
    // u01 = (cz-isz)(-C-iD)
    o[2] = -cz * C - sz * D; o[3] = sz * C - cz * D;
    // u10 = (cz+isz)(C-iD)
    o[4] = cz * C + sz * D;  o[5] = sz * C - cz * D;
    // u11 = (cz+isz)(A-iB) = conj(u00)
    o[6] = cz * A + sz * B;  o[7] = sz * A - cz * B;
}

template <int P>
__global__ __launch_bounds__(256) void pass_kernel(float2* __restrict__ st,
                                                   const float* __restrict__ utab,
                                                   const float* __restrict__ in_re,
                                                   const float* __restrict__ in_im) {
    constexpr PassT pt = make_pass(P);
    constexpr int NG = (P < 12) ? 5 : 4;
    constexpr int NS = 1 << NG;

    unsigned tid = blockIdx.x * 256u + threadIdx.x;
    unsigned batch = tid >> (16 - NG);
    unsigned T = tid & ((1u << (16 - NG)) - 1u);

    // scatter T's bits into the free (non-pivot) positions -> coset base
    unsigned base = 0;
    {
        unsigned tt = T;
        #pragma unroll
        for (int j = 0; j < 16; ++j)
            if ((pt.freemask >> j) & 1u) { base |= (tt & 1u) << j; tt >>= 1; }
    }
    size_t boff = (size_t)batch << 16;

    float xr[NS], xi[NS];
    #pragma unroll
    for (int v = 0; v < NS; ++v) {
        unsigned a = base ^ pt.combo[v];
        if constexpr (P == 0) {
            unsigned g4 = a ^ (a >> 4);           // initial gather absorbs final perm
            xr[v] = in_re[boff + g4];
            xi[v] = in_im[boff + g4];
        } else {
            float2 f = st[boff + a];
            xr[v] = f.x; xi[v] = f.y;
        }
    }

    #pragma unroll
    for (int g = 0; g < NG; ++g) {
        const float* u = utab + pt.gidx[g] * 8;
        float u00r = u[0], u00i = u[1], u01r = u[2], u01i = u[3];
        float u10r = u[4], u10i = u[5], u11r = u[6], u11i = u[7];
        int sg = __popc(pt.w[g] & base) & 1;
        // coefficient set for role = sg (c==0 slots); c==1 uses reversed order (D,C,B,A)
        float A0r = sg ? u11r : u00r, A0i = sg ? u11i : u00i;
        float B0r = sg ? u10r : u01r, B0i = sg ? u10i : u01i;
        float C0r = sg ? u01r : u10r, C0i = sg ? u01i : u10i;
        float D0r = sg ? u00r : u11r, D0i = sg ? u00i : u11i;
        #pragma unroll
        for (int v = 0; v < NS; ++v) {
            if (v & (1 << g)) continue;
            int c = __popc(pt.lam[g] & (unsigned)v) & 1;   // compile-time folds
            int y = v | (1 << g);
            float axr = xr[v], axi = xi[v], ayr = xr[y], ayi = xi[y];
            if (c == 0) {
                xr[v] = A0r * axr - A0i * axi + B0r * ayr - B0i * ayi;
                xi[v] = A0r * axi + A0i * axr + B0r * ayi + B0i * ayr;
                xr[y] = C0r * axr - C0i * axi + D0r * ayr - D0i * ayi;
                xi[y] = C0r * axi + C0i * axr + D0r * ayi + D0i * ayr;
            } else {
                xr[v] = D0r * axr - D0i * axi + C0r * ayr - C0i * ayi;
                xi[v] = D0r * axi + D0i * axr + C0r * ayi + C0i * ayr;
                xr[y] = B0r * axr - B0i * axi + A0r * ayr - A0i * ayi;
                xi[y] = B0r * axi + B0i * axr + A0r * ayi + A0i * ayr;
            }
        }
    }

    #pragma unroll
    for (int v = 0; v < NS; ++v) {
        unsigned a = base ^ pt.combo[v];
        st[boff + a] = make_float2(xr[v], xi[v]);
    }
}

extern "C" void kernel_launch(void* const* d_in, const int* in_sizes, int n_in,
                              void* d_out, int out_size, void* d_ws, size_t ws_size,
                              hipStream_t stream) {
    const float* in_re  = (const float*)d_in[0];
    const float* in_im  = (const float*)d_in[1];
    const float* params = (const float*)d_in[2];
    float2* st   = (float2*)d_out;
    float* utab  = (float*)d_ws;   // 64 gates * 8 floats = 2 KB

    prep_gates<<<dim3(1), dim3(64), 0, stream>>>(params, utab);

    #define LAUNCH_PASS(P)                                                          \
    {                                                                               \
        constexpr int ns = (P < 12) ? 32 : 16;                                      \
        int blocks = (int)(((unsigned)NBATCH * 65536u / ns) / 256u);                \
        pass_kernel<P><<<dim3(blocks), dim3(256), 0, stream>>>(st, utab, in_re, in_im); \
    }
    LAUNCH_PASS(0)  LAUNCH_PASS(1)  LAUNCH_PASS(2)  LAUNCH_PASS(3)
    LAUNCH_PASS(4)  LAUNCH_PASS(5)  LAUNCH_PASS(6)  LAUNCH_PASS(7)
    LAUNCH_PASS(8)  LAUNCH_PASS(9)  LAUNCH_PASS(10) LAUNCH_PASS(11)
    LAUNCH_PASS(12)
    #undef LAUNCH_PASS
}

// Round 3
// 515.304 us; speedup vs baseline: 1.6337x; 1.6337x over previous
//
#include <hip/hip_runtime.h>
#include <math.h>

// PQC simulator: 16 qubits, 4 layers, batch 256.
// Storage index = FINAL logical index (CNOT-chain perms deferred & pre-composed):
//   storage[s] init = in[s ^ (s>>4)]
//   gate (t,q): pairs {s, s^m'}, m' = prefixXOR^(4-t)(e_q); role(s)=parity(w'&s)
// 6 LDS passes; each block owns one coset of a dim<=13 subspace V (64KB tile).
// Layer-3 masks are FULL PREFIXES (bits 15-q..0), hence P5's 0x1FFF basis vector.

#define NLAYERS 4
#define NBATCH 256

constexpr unsigned mprime(int t, int q) {
    int u = NLAYERS - t, b = 15 - q;
    unsigned m = 0;
    for (int s = 0; s <= b; ++s) {
        int n = u - 1 + s;
        if ((n & s) == s) m |= 1u << (b - s);   // Lucas: C(n,s) odd iff (n&s)==s
    }
    return m;
}
constexpr unsigned wprime(int t, int q) {
    int u = NLAYERS - t, b = 15 - q;
    unsigned w = 0;
    for (int i = 0; b + i <= 15; ++i)
        if ((u & i) == i) w |= 1u << (b + i);
    return w;
}
constexpr int parity16(unsigned x) { int p = 0; for (int j = 0; j < 16; ++j) p ^= (int)((x >> j) & 1u); return p; }
constexpr int hibit(unsigned x) { int b = 0; for (int j = 0; j < 16; ++j) if ((x >> j) & 1u) b = j; return b; }

struct PassDef {
    int ng, dim, k, nfree;
    int gi[13];
    unsigned m[13], w[13], mu[13], rho[13];
    int piv[13];
    unsigned basis[13];
    int freebit[4];
};

constexpr PassDef make_pass(int P) {
    PassDef pd{};
    int tq[13][2] = {}; int ng = 0;
    if (P == 0) { for (int q = 3; q <= 15; ++q) { tq[ng][0] = 0; tq[ng][1] = q; ++ng; } }
    if (P == 1) { for (int q = 0; q <= 2; ++q) { tq[ng][0] = 0; tq[ng][1] = q; ++ng; }
                  for (int q = 6; q <= 15; ++q) { tq[ng][0] = 1; tq[ng][1] = q; ++ng; } }
    if (P == 2) { for (int q = 0; q <= 5; ++q) { tq[ng][0] = 1; tq[ng][1] = q; ++ng; }
                  for (int q = 9; q <= 15; ++q) { tq[ng][0] = 2; tq[ng][1] = q; ++ng; } }
    if (P == 3) { for (int q = 0; q <= 8; ++q) { tq[ng][0] = 2; tq[ng][1] = q; ++ng; }
                  for (int q = 12; q <= 15; ++q) { tq[ng][0] = 3; tq[ng][1] = q; ++ng; } }
    if (P == 4) { for (int q = 4; q <= 11; ++q) { tq[ng][0] = 3; tq[ng][1] = q; ++ng; } }
    if (P == 5) { for (int q = 0; q <= 3; ++q) { tq[ng][0] = 3; tq[ng][1] = q; ++ng; } }
    pd.ng = ng;

    int dim = 13, k = 13;
    if (P == 0) { k = 13; dim = 13; for (int j = 0; j < 13; ++j) pd.basis[j] = 1u << j; }
    if (P == 1) { k = 10; dim = 13; for (int j = 0; j < 10; ++j) pd.basis[j] = 1u << j;
                  pd.basis[10] = mprime(0, 2); pd.basis[11] = mprime(0, 1); pd.basis[12] = mprime(0, 0); }
    if (P == 2) { k = 7; dim = 13; for (int j = 0; j < 7; ++j) pd.basis[j] = 1u << j;
                  for (int j = 0; j < 6; ++j) pd.basis[7 + j] = mprime(1, 5 - j); }     // pivots 10..15
    if (P == 3) { k = 4; dim = 13; for (int j = 0; j < 4; ++j) pd.basis[j] = 1u << j;
                  for (int j = 0; j < 9; ++j) pd.basis[4 + j] = mprime(2, 8 - j); }     // pivots 7..15
    if (P == 4) { k = 12; dim = 12; for (int j = 0; j < 12; ++j) pd.basis[j] = 1u << j; }
    if (P == 5) { k = 9; dim = 13; for (int j = 0; j < 9; ++j) pd.basis[j] = 1u << j;
                  pd.basis[9]  = 0x1FFFu;        // pivot 12 (= mprime(3,3))
                  pd.basis[10] = 1u << 13;
                  pd.basis[11] = 1u << 14;
                  pd.basis[12] = 1u << 15; }
    pd.dim = dim; pd.k = k;

    int bpiv[13] = {};
    for (int j = 0; j < dim; ++j) bpiv[j] = hibit(pd.basis[j]);
    pd.nfree = 0;
    for (int bit = 0; bit < 16; ++bit) {
        bool isp = false;
        for (int j = 0; j < dim; ++j) if (bpiv[j] == bit) isp = true;
        if (!isp) pd.freebit[pd.nfree++] = bit;
    }
    for (int g = 0; g < ng; ++g) {
        int t = tq[g][0], q = tq[g][1];
        pd.gi[g] = t * 16 + q;
        pd.m[g] = mprime(t, q);
        pd.w[g] = wprime(t, q);
        unsigned r = pd.m[g], mu = 0;
        for (int iter = 0; iter < 17 && r != 0; ++iter) {
            int h = hibit(r);
            for (int j = 0; j < dim; ++j)
                if (bpiv[j] == h) { mu |= 1u << j; r ^= pd.basis[j]; break; }
        }
        mu = mu / (r == 0 ? 1u : 0u);             // compile error if m not in span(V)
        pd.mu[g] = mu;
        pd.piv[g] = hibit(mu);
        unsigned rho = 0;
        for (int j = 0; j < dim; ++j) rho |= (unsigned)parity16(pd.w[g] & pd.basis[j]) << j;
        pd.rho[g] = rho;
    }
    return pd;
}

// ---- prep: fuse RZ*RY*RX per (layer,qubit) into 8 floats in d_ws ----
__global__ void prep_gates(const float* __restrict__ params, float* __restrict__ utab) {
    int i = threadIdx.x;
    if (i >= 64) return;
    int t = i >> 4, q = i & 15;
    float ax = params[(t * 16 + q) * 3 + 0];
    float ay = params[(t * 16 + q) * 3 + 1];
    float az = params[(t * 16 + q) * 3 + 2];
    float cx = cosf(0.5f * ax), sx = sinf(0.5f * ax);
    float cy = cosf(0.5f * ay), sy = sinf(0.5f * ay);
    float cz = cosf(0.5f * az), sz = sinf(0.5f * az);
    float A = cy * cx, B = sy * sx, C = sy * cx, D = cy * sx;
    float* o = utab + i * 8;
    o[0] = cz * A + sz * B;  o[1] = cz * B - sz * A;
    o[2] = -cz * C - sz * D; o[3] = sz * C - cz * D;
    o[4] = cz * C + sz * D;  o[5] = sz * C - cz * D;
    o[6] = cz * A + sz * B;  o[7] = sz * A - cz * B;
}

template <int P>
__global__ __launch_bounds__(512) void pass_kernel(float2* __restrict__ st,
                                                   const float* __restrict__ utab,
                                                   const float* __restrict__ in_re,
                                                   const float* __restrict__ in_im) {
    constexpr PassDef pd = make_pass(P);
    constexpr int DIM = pd.dim;
    constexpr int NS = 1 << DIM;
    constexpr int NT = 512;
    constexpr unsigned LOWMASK = (1u << pd.k) - 1u;
    constexpr int NLD = NS / (2 * NT);
    constexpr int NPIT = (NS / 2) / NT;

    __shared__ float2 tile[NS];

    unsigned bid = blockIdx.x;
    unsigned batch = bid >> pd.nfree;
    unsigned cos = bid & ((1u << pd.nfree) - 1u);
    unsigned base = 0;
    #pragma unroll
    for (int i = 0; i < pd.nfree; ++i) base |= ((cos >> i) & 1u) << pd.freebit[i];
    size_t boff = (size_t)batch << 16;

    // ---- load tile ----
    #pragma unroll
    for (int it = 0; it < NLD; ++it) {
        unsigned l = 2u * ((unsigned)threadIdx.x + it * NT);
        unsigned addr = l & LOWMASK;
        #pragma unroll
        for (int j = pd.k; j < DIM; ++j)
            if ((l >> j) & 1u) addr ^= pd.basis[j];
        unsigned ga = base ^ addr;
        if constexpr (P == 0) {
            unsigned g4 = ga ^ (ga >> 4);          // gather absorbs final permutation
            unsigned ge = g4 & ~1u;
            bool odd = (g4 & 1u) != 0;
            float2 vr = *(const float2*)(in_re + boff + ge);
            float2 vi = *(const float2*)(in_im + boff + ge);
            tile[l]     = odd ? make_float2(vr.y, vi.y) : make_float2(vr.x, vi.x);
            tile[l + 1] = odd ? make_float2(vr.x, vi.x) : make_float2(vr.y, vi.y);
        } else {
            unsigned ge = ga & ~1u;
            bool odd = (ga & 1u) != 0;
            float4 v = *(const float4*)(st + boff + ge);
            tile[l]     = odd ? make_float2(v.z, v.w) : make_float2(v.x, v.y);
            tile[l + 1] = odd ? make_float2(v.x, v.y) : make_float2(v.z, v.w);
        }
    }
    __syncthreads();

    // ---- gates ----
    #pragma unroll
    for (int g = 0; g < pd.ng; ++g) {
        const float* u = utab + pd.gi[g] * 8;
        int pbase = __popc(pd.w[g] & base) & 1;    // block-uniform
        float Ar = pbase ? u[6] : u[0], Ai = pbase ? u[7] : u[1];
        float Br = pbase ? u[4] : u[2], Bi = pbase ? u[5] : u[3];
        float Cr = pbase ? u[2] : u[4], Ci = pbase ? u[3] : u[5];
        float Dr = pbase ? u[0] : u[6], Di = pbase ? u[1] : u[7];
        unsigned MU = pd.mu[g], RHO = pd.rho[g];
        int t = pd.piv[g];
        #pragma unroll
        for (int it2 = 0; it2 < NPIT; ++it2) {
            unsigned p = (unsigned)threadIdx.x + it2 * NT;
            unsigned l0 = ((p >> t) << (t + 1)) | (p & ((1u << t) - 1u));
            int rr = __popc(l0 & RHO) & 1;
            if (MU == 1u) {                         // adjacent pair: float4 LDS path
                float4 v = *(const float4*)&tile[l0];
                float s0r = rr ? v.z : v.x, s0i = rr ? v.w : v.y;
                float s1r = rr ? v.x : v.z, s1i = rr ? v.y : v.w;
                float n0r = Ar * s0r - Ai * s0i + Br * s1r - Bi * s1i;
                float n0i = Ar * s0i + Ai * s0r + Br * s1i + Bi * s1r;
                float n1r = Cr * s0r - Ci * s0i + Dr * s1r - Di * s1i;
                float n1i = Cr * s0i + Ci * s0r + Dr * s1i + Di * s1r;
                float4 o = rr ? make_float4(n1r, n1i, n0r, n0i)
                              : make_float4(n0r, n0i, n1r, n1i);
                *(float4*)&tile[l0] = o;
            } else {
                unsigned l1 = l0 ^ MU;
                unsigned la = rr ? l1 : l0;         // logical |0> side address
                unsigned lb = rr ? l0 : l1;
                float2 x0 = tile[la], x1 = tile[lb];
                float n0r = Ar * x0.x - Ai * x0.y + Br * x1.x - Bi * x1.y;
                float n0i = Ar * x0.y + Ai * x0.x + Br * x1.y + Bi * x1.x;
                float n1r = Cr * x0.x - Ci * x0.y + Dr * x1.x - Di * x1.y;
                float n1i = Cr * x0.y + Ci * x0.x + Dr * x1.y + Di * x1.x;
                tile[la] = make_float2(n0r, n0i);
                tile[lb] = make_float2(n1r, n1i);
            }
        }
        __syncthreads();
    }

    // ---- store tile ----
    #pragma unroll
    for (int it = 0; it < NLD; ++it) {
        unsigned l = 2u * ((unsigned)threadIdx.x + it * NT);
        unsigned addr = l & LOWMASK;
        #pragma unroll
        for (int j = pd.k; j < DIM; ++j)
            if ((l >> j) & 1u) addr ^= pd.basis[j];
        unsigned ga = base ^ addr;
        unsigned ge = ga & ~1u;
        bool odd = (ga & 1u) != 0;
        float2 a0 = tile[l], a1 = tile[l + 1];
        float4 v = odd ? make_float4(a1.x, a1.y, a0.x, a0.y)
                       : make_float4(a0.x, a0.y, a1.x, a1.y);
        *(float4*)(st + boff + ge) = v;
    }
}

extern "C" void kernel_launch(void* const* d_in, const int* in_sizes, int n_in,
                              void* d_out, int out_size, void* d_ws, size_t ws_size,
                              hipStream_t stream) {
    const float* in_re  = (const float*)d_in[0];
    const float* in_im  = (const float*)d_in[1];
    const float* params = (const float*)d_in[2];
    float2* st  = (float2*)d_out;
    float* utab = (float*)d_ws;      // 64 gates * 8 floats = 2 KB

    prep_gates<<<dim3(1), dim3(64), 0, stream>>>(params, utab);

    pass_kernel<0><<<dim3(2048), dim3(512), 0, stream>>>(st, utab, in_re, in_im);
    pass_kernel<1><<<dim3(2048), dim3(512), 0, stream>>>(st, utab, in_re, in_im);
    pass_kernel<2><<<dim3(2048), dim3(512), 0, stream>>>(st, utab, in_re, in_im);
    pass_kernel<3><<<dim3(2048), dim3(512), 0, stream>>>(st, utab, in_re, in_im);
    pass_kernel<4><<<dim3(4096), dim3(512), 0, stream>>>(st, utab, in_re, in_im);
    pass_kernel<5><<<dim3(2048), dim3(512), 0, stream>>>(st, utab, in_re, in_im);
}